// Round 1
// 367.159 us; speedup vs baseline: 1.5710x; 1.5710x over previous
//
#include <hip/hip_runtime.h>
#include <stdint.h>

#define BDIM 2048
#define KDIM 768
#define NTOT 16140
#define NKT 24   // 768 / 32

typedef _Float16 half8 __attribute__((ext_vector_type(8)));
typedef float floatx4 __attribute__((ext_vector_type(4)));

__device__ __forceinline__ unsigned short f2h(float f) {
  _Float16 h = (_Float16)f;
  return __builtin_bit_cast(unsigned short, h);
}

__device__ __forceinline__ void level_of(int col, int& cb, int& Cl, long long& ob) {
  if      (col < 20)   { cb = 0;    Cl = 20;    ob = 0LL; }
  else if (col < 90)   { cb = 20;   Cl = 70;    ob = 40960LL; }
  else if (col < 340)  { cb = 90;   Cl = 250;   ob = 184320LL; }
  else if (col < 1140) { cb = 340;  Cl = 800;   ob = 696320LL; }
  else if (col < 4140) { cb = 1140; Cl = 3000;  ob = 2334720LL; }
  else                 { cb = 4140; Cl = 12000; ob = 8478720LL; }
}

// direct global->LDS async copy, 16B per lane; lds dst = uniform base + lane*16
__device__ __forceinline__ void gload_lds16(const void* g, void* l) {
  __builtin_amdgcn_global_load_lds(
      (const __attribute__((address_space(1))) unsigned int*)g,
      (__attribute__((address_space(3))) unsigned int*)l, 16, 0, 0);
}

// ---------------- fp32 -> fp16 conversion of x and all W (concatenated) ----------------
__global__ __launch_bounds__(256) void convert_kernel(
    const float* __restrict__ x,
    const float* __restrict__ W0, const float* __restrict__ W1,
    const float* __restrict__ W2, const float* __restrict__ W3,
    const float* __restrict__ W4, const float* __restrict__ W5,
    unsigned short* __restrict__ xh, unsigned short* __restrict__ wh)
{
  long long i4 = (long long)blockIdx.x * 256 + threadIdx.x;
  if (i4 >= 3492096LL) return;              // (2048*768 + 16140*768)/4
  long long e = i4 * 4;
  const long long XN = (long long)BDIM * KDIM;  // 1,572,864
  float4 v;
  unsigned short* dst;
  if (e < XN) {
    v = reinterpret_cast<const float4*>(x)[i4];
    dst = xh + e;
  } else {
    long long we = e - XN;
    const float* src; long long off;
    if      (we < 15360)    { src = W0; off = we; }
    else if (we < 69120)    { src = W1; off = we - 15360; }
    else if (we < 261120)   { src = W2; off = we - 69120; }
    else if (we < 875520)   { src = W3; off = we - 261120; }
    else if (we < 3179520)  { src = W4; off = we - 875520; }
    else                    { src = W5; off = we - 3179520; }
    v = reinterpret_cast<const float4*>(src)[off >> 2];
    dst = wh + we;
  }
  ushort4 o;
  o.x = f2h(v.x); o.y = f2h(v.y); o.z = f2h(v.z); o.w = f2h(v.w);
  *reinterpret_cast<ushort4*>(dst) = o;
}

// ---------------- segment-start tables (lower_bound over sorted parent arrays) ----------------
__global__ __launch_bounds__(256) void seg_build_kernel(
    const int* __restrict__ p1, const int* __restrict__ p2, const int* __restrict__ p3,
    const int* __restrict__ p4, const int* __restrict__ p5, int* __restrict__ seg)
{
  int idx = blockIdx.x * 256 + threadIdx.x;
  if (idx >= 4147) return;
  int L, s;
  if      (idx < 2)    { L = 0; s = idx; }
  else if (idx < 23)   { L = 1; s = idx - 2; }
  else if (idx < 94)   { L = 2; s = idx - 23; }
  else if (idx < 345)  { L = 3; s = idx - 94; }
  else if (idx < 1146) { L = 4; s = idx - 345; }
  else                 { L = 5; s = idx - 1146; }
  int val;
  if (L == 0) {
    val = (s == 0) ? 0 : 20;
  } else {
    const int* p = (L == 1) ? p1 : (L == 2) ? p2 : (L == 3) ? p3 : (L == 4) ? p4 : p5;
    int C = (L == 1) ? 70 : (L == 2) ? 250 : (L == 3) ? 800 : (L == 4) ? 3000 : 12000;
    int lo = 0, hi = C;
    while (lo < hi) { int mid = (lo + hi) >> 1; if (p[mid] < s) lo = mid + 1; else hi = mid; }
    val = lo;
  }
  seg[idx] = val;
}

// ---------------- fp16 MFMA GEMM: logits = x @ Wcat^T ----------------
// m97 structure: global_load_lds width-16 into double-buffered LDS, 1 barrier/K-step.
// LDS layout (linear, required by global_load_lds): A[2][128 rows][32 halfs] then B[2][...]
//   A buf b at byte b*8192, B buf b at 16384 + b*8192; row stride 64 B.
#define EPI_STRIDE 132 // floats per staged C row (132 mod 32 = 4 -> conflict-free)

__global__ __launch_bounds__(256, 2) void gemm_kernel(
    const unsigned short* __restrict__ Ah,   // [2048][768] fp16
    const unsigned short* __restrict__ Wh,   // [16140][768] fp16
    float* __restrict__ out)
{
  __shared__ __align__(16) char smem_raw[64 * EPI_STRIDE * 4];  // 33792 B; staging uses 32768
  float* epi = (float*)smem_raw;

  // XCD-aware swizzle (2032 = 8*254, bijective)
  const int bid = blockIdx.x;
  const int logical = (bid & 7) * 254 + (bid >> 3);
  const int cx = logical >> 4;                // col tile 0..126
  const int row0 = (logical & 15) * 128;
  const int col0 = cx * 128;

  const int tid  = threadIdx.x;
  const int wave = tid >> 6;
  const int lane = tid & 63;
  const int wr = (wave >> 1) * 64;
  const int wc = (wave & 1) * 64;
  const int q  = lane >> 4;
  const int lr = lane & 15;

  // staging decomposition: each wave stages 2 chunks of A and 2 of B per K-step;
  // chunk c = 16 rows; lane -> row 16c + (lane>>2), 16B slot (lane&3) within the 64B row.
  const int rquad = lane >> 2;
  const int kq = lane & 3;

  floatx4 acc[4][4];
#pragma unroll
  for (int i = 0; i < 4; ++i)
#pragma unroll
    for (int j = 0; j < 4; ++j)
      acc[i][j] = (floatx4){0.f, 0.f, 0.f, 0.f};

  // per-wave, per-chunk global base addresses (halfs); add kt*32 per K-step
  const unsigned short* gA[2];
  const unsigned short* gB[2];
#pragma unroll
  for (int i = 0; i < 2; ++i) {
    int c = 2 * wave + i;
    int rowA = row0 + 16 * c + rquad;
    gA[i] = Ah + (long long)rowA * KDIM + kq * 8;
    int colB = col0 + 16 * c + rquad;
    if (colB >= NTOT) colB = NTOT - 1;
    gB[i] = Wh + (long long)colB * KDIM + kq * 8;
  }

  auto stage = [&](int buf, int kt) {
#pragma unroll
    for (int i = 0; i < 2; ++i) {
      int c = 2 * wave + i;
      gload_lds16(gA[i] + kt * 32, smem_raw + buf * 8192 + c * 1024);
      gload_lds16(gB[i] + kt * 32, smem_raw + 16384 + buf * 8192 + c * 1024);
    }
  };

  int cur = 0;
  stage(0, 0);
  __syncthreads();   // compiler emits vmcnt(0) before s_barrier -> buf0 ready

  for (int kt = 0; kt < NKT; ++kt) {
    if (kt + 1 < NKT) stage(cur ^ 1, kt + 1);   // async prefetch, drained at the barrier below
    const char* Ac = smem_raw + cur * 8192;
    const char* Bc = smem_raw + 16384 + cur * 8192;
    half8 af[4], bf[4];
#pragma unroll
    for (int i = 0; i < 4; ++i)
      af[i] = __builtin_bit_cast(half8, *(const uint4*)(Ac + (wr + i * 16 + lr) * 64 + q * 16));
#pragma unroll
    for (int j = 0; j < 4; ++j)
      bf[j] = __builtin_bit_cast(half8, *(const uint4*)(Bc + (wc + j * 16 + lr) * 64 + q * 16));
#pragma unroll
    for (int i = 0; i < 4; ++i)
#pragma unroll
      for (int j = 0; j < 4; ++j)
        acc[i][j] = __builtin_amdgcn_mfma_f32_16x16x32_f16(af[i], bf[j], acc[i][j], 0, 0, 0);
    __syncthreads();  // drains vmcnt(0): next buf staged; also fences reads of cur buf
    cur ^= 1;
  }

  // ---- epilogue: stage C-tile through LDS, write coalesced float4 rows ----
  int cbA, ClA; long long obA; level_of(col0, cbA, ClA, obA);
  int cbB, ClB; long long obB; level_of(col0 + 127, cbB, ClB, obB);
  const bool fast = (cbA == cbB) && ((cbA & 3) == 0) && ((ClA & 3) == 0) && (col0 + 128 <= NTOT);

  for (int h = 0; h < 2; ++h) {
    __syncthreads();
    if ((wave >> 1) == h) {
#pragma unroll
      for (int i = 0; i < 4; ++i)
#pragma unroll
        for (int j = 0; j < 4; ++j)
#pragma unroll
          for (int rg = 0; rg < 4; ++rg)
            epi[(i * 16 + q * 4 + rg) * EPI_STRIDE + wc + j * 16 + lr] = acc[i][j][rg];
    }
    __syncthreads();
    if (fast) {
      const long long rowbase = obA + (long long)(row0 + h * 64) * ClA + (col0 - cbA);
#pragma unroll
      for (int it = 0; it < 8; ++it) {
        int idx = it * 256 + tid;
        int r = idx >> 5, f4 = idx & 31;
        float4 v = *(const float4*)(epi + r * EPI_STRIDE + f4 * 4);
        *(float4*)(out + rowbase + (long long)r * ClA + f4 * 4) = v;
      }
    } else {
      for (int idx = tid; idx < 64 * 128; idx += 256) {
        int r = idx >> 7, c = idx & 127;
        int col = col0 + c;
        if (col < NTOT) {
          int cb, Cl; long long ob; level_of(col, cb, Cl, ob);
          out[ob + (long long)(row0 + h * 64 + r) * Cl + (col - cb)] = epi[r * EPI_STRIDE + c];
        }
      }
    }
  }
}

// ---------------- fused 6-level segment softmax, one row per block ----------------
// Column-parallel exp and scale (float4 on levels 0/3/4/5 = 98% of columns);
// only segment sums iterate children. 512 threads, LDS 76.5 KB -> 2 blocks/CU (16 waves).
__global__ __launch_bounds__(512) void tree_softmax_kernel(
    float* __restrict__ out,
    const float* __restrict__ b0, const float* __restrict__ b1, const float* __restrict__ b2,
    const float* __restrict__ b3, const float* __restrict__ b4, const float* __restrict__ b5,
    const int* __restrict__ seg,
    const int* __restrict__ p1, const int* __restrict__ p2, const int* __restrict__ p3,
    const int* __restrict__ p4, const int* __restrict__ p5)
{
  __shared__ __align__(16) float l[NTOT];   // 64560 B — e-values then probs, all levels
  __shared__ float rs[3000];                // per-parent p_parent/segsum for current level
  const int tid = threadIdx.x;
  const int row = blockIdx.x;
  const float* bias[6] = {b0, b1, b2, b3, b4, b5};
  const int* par[6] = {nullptr, p1, p2, p3, p4, p5};
  const int Cn[6] = {20, 70, 250, 800, 3000, 12000};
  const int Pn[6] = {1, 20, 70, 250, 800, 3000};
  const int lb[6] = {0, 20, 90, 340, 1140, 4140};
  const int so[6] = {0, 2, 23, 94, 345, 1146};
  const long long ob[6] = {0, 40960, 184320, 696320, 2334720, 8478720};

  // phase 1: e = exp(logit + bias), column-parallel (vectorized where 16B-aligned)
#pragma unroll
  for (int L = 0; L < 6; ++L) {
    const float* src = out + ob[L] + (long long)row * Cn[L];
    const float* bs = bias[L];
    float* dst = l + lb[L];
    if ((Cn[L] & 3) == 0 && (lb[L] & 3) == 0) {
      const int n4 = Cn[L] >> 2;
      for (int i = tid; i < n4; i += 512) {
        float4 v = reinterpret_cast<const float4*>(src)[i];
        float4 b = reinterpret_cast<const float4*>(bs)[i];
        float4 e;
        e.x = __expf(v.x + b.x); e.y = __expf(v.y + b.y);
        e.z = __expf(v.z + b.z); e.w = __expf(v.w + b.w);
        reinterpret_cast<float4*>(dst)[i] = e;
      }
    } else {
      for (int c = tid; c < Cn[L]; c += 512) dst[c] = __expf(src[c] + bs[c]);
    }
  }
  __syncthreads();

  // phases 2..: per level, segment sums (reads only) then column-parallel scale+store
#pragma unroll
  for (int L = 0; L < 6; ++L) {
    const int* sg = seg + so[L];
    float* lv = l + lb[L];
    const float* pv = l + ((L == 0) ? 0 : lb[L - 1]);  // parent probs (final)
    for (int s = tid; s < Pn[L]; s += 512) {
      int st = sg[s], en = sg[s + 1];
      float sum = 0.f;
      for (int c = st; c < en; ++c) sum += lv[c];
      float pp = (L == 0) ? 1.0f : pv[s];
      rs[s] = pp / sum;   // empty segment -> inf/nan, never gathered
    }
    __syncthreads();
    float* dstg = out + ob[L] + (long long)row * Cn[L];
    if (L == 0) {
      float r0 = rs[0];
      for (int c = tid; c < 20; c += 512) { float v = lv[c] * r0; lv[c] = v; dstg[c] = v; }
    } else if ((Cn[L] & 3) == 0 && (lb[L] & 3) == 0) {
      const int* pa = par[L];
      const int n4 = Cn[L] >> 2;
      for (int i = tid; i < n4; i += 512) {
        int4 pi = reinterpret_cast<const int4*>(pa)[i];
        float4 v = reinterpret_cast<const float4*>(lv)[i];
        v.x *= rs[pi.x]; v.y *= rs[pi.y]; v.z *= rs[pi.z]; v.w *= rs[pi.w];
        if (L != 5) reinterpret_cast<float4*>(lv)[i] = v;  // next level reads parent probs
        reinterpret_cast<float4*>(dstg)[i] = v;
      }
    } else {
      const int* pa = par[L];
      for (int c = tid; c < Cn[L]; c += 512) {
        float v = lv[c] * rs[pa[c]];
        lv[c] = v; dstg[c] = v;
      }
    }
    __syncthreads();
  }
}

extern "C" void kernel_launch(void* const* d_in, const int* in_sizes, int n_in,
                              void* d_out, int out_size, void* d_ws, size_t ws_size,
                              hipStream_t stream)
{
  const float* x = (const float*)d_in[0];
  const float* W[6]    = {(const float*)d_in[1], (const float*)d_in[3], (const float*)d_in[5],
                          (const float*)d_in[7], (const float*)d_in[9], (const float*)d_in[11]};
  const float* bias[6] = {(const float*)d_in[2], (const float*)d_in[4], (const float*)d_in[6],
                          (const float*)d_in[8], (const float*)d_in[10], (const float*)d_in[12]};
  const int* p[5] = {(const int*)d_in[13], (const int*)d_in[14], (const int*)d_in[15],
                     (const int*)d_in[16], (const int*)d_in[17]};
  float* out = (float*)d_out;
  char* ws = (char*)d_ws;
  unsigned short* xh = (unsigned short*)ws;                  // 3,145,728 B
  unsigned short* wh = (unsigned short*)(ws + 3145728);      // 24,791,040 B
  int* seg = (int*)(ws + 27936768);                          // 4147 ints

  convert_kernel<<<13641, 256, 0, stream>>>(x, W[0], W[1], W[2], W[3], W[4], W[5], xh, wh);
  seg_build_kernel<<<17, 256, 0, stream>>>(p[0], p[1], p[2], p[3], p[4], seg);
  gemm_kernel<<<2032, 256, 0, stream>>>(xh, wh, out);
  tree_softmax_kernel<<<2048, 512, 0, stream>>>(
      out, bias[0], bias[1], bias[2], bias[3], bias[4], bias[5], seg,
      p[0], p[1], p[2], p[3], p[4]);
}